// Round 6
// baseline (172.088 us; speedup 1.0000x reference)
//
#include <hip/hip_runtime.h>
#include <hip/hip_bf16.h>

#define NB 8
#define NPTS 20000
#define DD 128
#define MM 1024
#define INV_T (1.0f/0.07f)
#define NTILES (NB*8*8)   // 512 tile-blocks

typedef __attribute__((ext_vector_type(8))) short bf16x8;
typedef __attribute__((ext_vector_type(4))) float f32x4;

// K1: one wave per correspondence PAIR: load both rows, one butterfly for
// {|f0|^2, |f1|^2, <f0,f1>}, write both normalized bf16 rows + fp32 diag
// logit. Also zeroes colsum + completion counter. No fences (agent fences
// = L2 flush on gfx950, R2 lesson: 55us/dispatch).
__global__ __launch_bounds__(256) void gather_pairs(
    const float* __restrict__ feats0, const float* __restrict__ feats1,
    const int* __restrict__ corrs,   // int32 words; may actually be int64 pairs
    __hip_bfloat16* __restrict__ f0s, __hip_bfloat16* __restrict__ f1s,
    float* __restrict__ colsum, float* __restrict__ diag,
    unsigned int* __restrict__ cnt)
{
    int tid  = threadIdx.x;
    int lane = tid & 63;
    int wv   = tid >> 6;
    int pid  = blockIdx.x * 4 + wv;      // [0, NB*MM)

    // zero colsum (8192 floats) + cnt; kernel boundary orders this vs K2
    if (blockIdx.x < 32) colsum[blockIdx.x * 256 + tid] = 0.0f;
    if (blockIdx.x == 32 && tid == 0) *cnt = 0u;

    // Detect corrs dtype: int64 data has zero hi-words in the first 32 values.
    int probe = (lane < 32) ? corrs[2*lane + 1] : 0;
    bool is64 = (__ballot(probe != 0) == 0ULL);

    int b = pid >> 10;
    int m = pid & (MM - 1);

    int w0 = (b*MM + m)*2;               // corrs[b,m,0], corrs[b,m,1]
    int idx0 = is64 ? corrs[w0*2]     : corrs[w0];
    int idx1 = is64 ? corrs[w0*2 + 2] : corrs[w0 + 1];

    const float* r0 = feats0 + ((size_t)b * NPTS + (size_t)idx0) * DD;
    const float* r1 = feats1 + ((size_t)b * NPTS + (size_t)idx1) * DD;

    float2 v0 = ((const float2*)r0)[lane];
    float2 v1 = ((const float2*)r1)[lane];
    float ss0 = v0.x*v0.x + v0.y*v0.y;
    float ss1 = v1.x*v1.x + v1.y*v1.y;
    float dp  = v0.x*v1.x + v0.y*v1.y;
    #pragma unroll
    for (int off = 32; off >= 1; off >>= 1) {
        ss0 += __shfl_xor(ss0, off);
        ss1 += __shfl_xor(ss1, off);
        dp  += __shfl_xor(dp,  off);
    }
    float s0 = 1.0f / fmaxf(sqrtf(ss0), 1e-12f);
    float s1 = 1.0f / fmaxf(sqrtf(ss1), 1e-12f);

    if (lane == 0)
        diag[b*MM + m] = dp * s0 * s1 * INV_T;

    __hip_bfloat162 h0, h1;
    h0.x = __float2bfloat16(v0.x * s0);
    h0.y = __float2bfloat16(v0.y * s0);
    h1.x = __float2bfloat16(v1.x * s1);
    h1.y = __float2bfloat16(v1.y * s1);
    ((__hip_bfloat162*)(f0s + (size_t)(b*MM + m) * DD))[lane] = h0;
    ((__hip_bfloat162*)(f1s + (size_t)(b*MM + m) * DD))[lane] = h1;
}

// K2: per (b, ti, tj) 128x128 logits tile via MFMA bf16; exp + per-column
// atomicAdd into colsum. Fused fence-free finalize: __syncthreads drains
// vmcnt (adds reach the coherent point), relaxed agent counter picks the
// last block, which re-reads colsum via relaxed agent atomic loads (no
// wbl2 anywhere) and writes the loss.
__global__ __launch_bounds__(256) void logits_fused(
    const short* __restrict__ f1s, const short* __restrict__ f0s,
    float* __restrict__ colsum, const float* __restrict__ diag,
    unsigned int* __restrict__ cnt, float* __restrict__ out)
{
    int tj = blockIdx.x, ti = blockIdx.y, b = blockIdx.z;
    int tid  = threadIdx.x;
    int w    = tid >> 6;
    int lane = tid & 63;
    int n16  = lane & 15;
    int quad = lane >> 4;

    const short* Abase = f1s + (size_t)(b*MM + ti*128 + w*32 + n16) * DD;
    const short* Bbase = f0s + (size_t)(b*MM + tj*128 + n16) * DD;

    f32x4 acc[2][8];
    #pragma unroll
    for (int fr = 0; fr < 2; fr++)
        #pragma unroll
        for (int fc = 0; fc < 8; fc++)
            acc[fr][fc] = {0.f, 0.f, 0.f, 0.f};

    #pragma unroll
    for (int ks = 0; ks < 4; ks++) {
        int koff = ks*32 + quad*8;
        bf16x8 a[2], bb[8];
        #pragma unroll
        for (int fr = 0; fr < 2; fr++)
            a[fr] = *(const bf16x8*)(Abase + fr*16*DD + koff);
        #pragma unroll
        for (int fc = 0; fc < 8; fc++)
            bb[fc] = *(const bf16x8*)(Bbase + fc*16*DD + koff);
        #pragma unroll
        for (int fr = 0; fr < 2; fr++)
            #pragma unroll
            for (int fc = 0; fc < 8; fc++)
                acc[fr][fc] = __builtin_amdgcn_mfma_f32_16x16x32_bf16(
                    a[fr], bb[fc], acc[fr][fc], 0, 0, 0);
    }

    __shared__ float lcol[128];
    if (tid < 128) lcol[tid] = 0.f;
    __syncthreads();

    #pragma unroll
    for (int fc = 0; fc < 8; fc++) {
        float s = 0.f;
        #pragma unroll
        for (int fr = 0; fr < 2; fr++) {
            #pragma unroll
            for (int r = 0; r < 4; r++)
                s += __expf(acc[fr][fc][r] * INV_T);
        }
        s += __shfl_xor(s, 16);
        s += __shfl_xor(s, 32);
        if (quad == 0) atomicAdd(&lcol[fc*16 + n16], s);
    }
    __syncthreads();
    if (tid < 128) atomicAdd(&colsum[b*MM + tj*128 + tid], lcol[tid]);

    // --- fence-free last-block finalize ---
    __syncthreads();   // drains each wave's vmcnt: colsum adds are at the
                       // coherent point before any thread passes this barrier
    __shared__ unsigned int lastflag;
    if (tid == 0)
        lastflag = __hip_atomic_fetch_add(cnt, 1u, __ATOMIC_RELAXED,
                                          __HIP_MEMORY_SCOPE_AGENT);
    __syncthreads();
    if (lastflag == NTILES - 1) {
        float accl = 0.f;
        for (int k = tid; k < NB*MM; k += 256) {
            float cs = __hip_atomic_load(&colsum[k], __ATOMIC_RELAXED,
                                         __HIP_MEMORY_SCOPE_AGENT);
            accl += diag[k] - __logf(cs);
        }
        #pragma unroll
        for (int off = 32; off >= 1; off >>= 1) accl += __shfl_xor(accl, off);
        __shared__ float wsum[4];
        if (lane == 0) wsum[w] = accl;
        __syncthreads();
        if (tid == 0)
            out[0] = -(wsum[0] + wsum[1] + wsum[2] + wsum[3]) * (1.0f / (NB*MM));
    }
}

extern "C" void kernel_launch(void* const* d_in, const int* in_sizes, int n_in,
                              void* d_out, int out_size, void* d_ws, size_t ws_size,
                              hipStream_t stream)
{
    const float* feats0 = (const float*)d_in[0];
    const float* feats1 = (const float*)d_in[1];
    const int*   corrs  = (const int*)d_in[2];

    char* ws = (char*)d_ws;
    __hip_bfloat16* f0s = (__hip_bfloat16*)ws;                              // 2 MB
    __hip_bfloat16* f1s = (__hip_bfloat16*)(ws + (size_t)NB*MM*DD*2);       // 2 MB
    float* colsum = (float*)(ws + 2*(size_t)NB*MM*DD*2);                    // 32 KB
    float* diag   = colsum + NB*MM;                                         // 32 KB
    unsigned int* cnt = (unsigned int*)(diag + NB*MM);                      // 4 B

    gather_pairs<<<(NB*MM)/4, 256, 0, stream>>>(feats0, feats1, corrs,
                                                f0s, f1s, colsum, diag, cnt);
    logits_fused<<<dim3(8, 8, NB), 256, 0, stream>>>((const short*)f1s,
                                                     (const short*)f0s,
                                                     colsum, diag, cnt,
                                                     (float*)d_out);
}

// Round 7
// 159.487 us; speedup vs baseline: 1.0790x; 1.0790x over previous
//
#include <hip/hip_runtime.h>
#include <hip/hip_bf16.h>

#define NB 8
#define NPTS 20000
#define DD 128
#define MM 1024
#define INV_T (1.0f/0.07f)

typedef __attribute__((ext_vector_type(8))) short bf16x8;
typedef __attribute__((ext_vector_type(4))) float f32x4;

// K1: one wave per correspondence PAIR: load both rows, one butterfly for
// {|f0|^2, |f1|^2, <f0,f1>}, write both normalized bf16 rows + fp32 diag
// logit. Also zeroes colsum. No fences (agent fences = L2 flush, R2 lesson),
// no last-block fusion (coherent-point readback tail, R6 lesson).
__global__ __launch_bounds__(256) void gather_pairs(
    const float* __restrict__ feats0, const float* __restrict__ feats1,
    const int* __restrict__ corrs,   // int32 words; may actually be int64 pairs
    __hip_bfloat16* __restrict__ f0s, __hip_bfloat16* __restrict__ f1s,
    float* __restrict__ colsum, float* __restrict__ diag)
{
    int tid  = threadIdx.x;
    int lane = tid & 63;
    int wv   = tid >> 6;
    int pid  = blockIdx.x * 4 + wv;      // [0, NB*MM)

    // zero colsum (8192 floats); kernel boundary orders this vs K2
    if (blockIdx.x < 32) colsum[blockIdx.x * 256 + tid] = 0.0f;

    // Detect corrs dtype: int64 data has zero hi-words in the first 32 values.
    int probe = (lane < 32) ? corrs[2*lane + 1] : 0;
    bool is64 = (__ballot(probe != 0) == 0ULL);

    int b = pid >> 10;
    int m = pid & (MM - 1);

    int w0 = (b*MM + m)*2;               // corrs[b,m,0], corrs[b,m,1]
    int idx0 = is64 ? corrs[w0*2]     : corrs[w0];
    int idx1 = is64 ? corrs[w0*2 + 2] : corrs[w0 + 1];

    const float* r0 = feats0 + ((size_t)b * NPTS + (size_t)idx0) * DD;
    const float* r1 = feats1 + ((size_t)b * NPTS + (size_t)idx1) * DD;

    float2 v0 = ((const float2*)r0)[lane];
    float2 v1 = ((const float2*)r1)[lane];
    float ss0 = v0.x*v0.x + v0.y*v0.y;
    float ss1 = v1.x*v1.x + v1.y*v1.y;
    float dp  = v0.x*v1.x + v0.y*v1.y;
    #pragma unroll
    for (int off = 32; off >= 1; off >>= 1) {
        ss0 += __shfl_xor(ss0, off);
        ss1 += __shfl_xor(ss1, off);
        dp  += __shfl_xor(dp,  off);
    }
    float s0 = 1.0f / fmaxf(sqrtf(ss0), 1e-12f);
    float s1 = 1.0f / fmaxf(sqrtf(ss1), 1e-12f);

    if (lane == 0)
        diag[b*MM + m] = dp * s0 * s1 * INV_T;

    __hip_bfloat162 h0, h1;
    h0.x = __float2bfloat16(v0.x * s0);
    h0.y = __float2bfloat16(v0.y * s0);
    h1.x = __float2bfloat16(v1.x * s1);
    h1.y = __float2bfloat16(v1.y * s1);
    ((__hip_bfloat162*)(f0s + (size_t)(b*MM + m) * DD))[lane] = h0;
    ((__hip_bfloat162*)(f1s + (size_t)(b*MM + m) * DD))[lane] = h1;
}

// K2: per (b, ti, tj) 128x128 logits tile via MFMA bf16. Epilogue: exp +
// per-column partial sums -> global atomicAdd. No diag logic (K1 owns diag).
__global__ __launch_bounds__(256) void logits_lse(
    const short* __restrict__ f1s, const short* __restrict__ f0s,
    float* __restrict__ colsum)
{
    int tj = blockIdx.x, ti = blockIdx.y, b = blockIdx.z;
    int tid  = threadIdx.x;
    int w    = tid >> 6;
    int lane = tid & 63;
    int n16  = lane & 15;
    int quad = lane >> 4;

    const short* Abase = f1s + (size_t)(b*MM + ti*128 + w*32 + n16) * DD;
    const short* Bbase = f0s + (size_t)(b*MM + tj*128 + n16) * DD;

    f32x4 acc[2][8];
    #pragma unroll
    for (int fr = 0; fr < 2; fr++)
        #pragma unroll
        for (int fc = 0; fc < 8; fc++)
            acc[fr][fc] = {0.f, 0.f, 0.f, 0.f};

    #pragma unroll
    for (int ks = 0; ks < 4; ks++) {
        int koff = ks*32 + quad*8;
        bf16x8 a[2], bb[8];
        #pragma unroll
        for (int fr = 0; fr < 2; fr++)
            a[fr] = *(const bf16x8*)(Abase + fr*16*DD + koff);
        #pragma unroll
        for (int fc = 0; fc < 8; fc++)
            bb[fc] = *(const bf16x8*)(Bbase + fc*16*DD + koff);
        #pragma unroll
        for (int fr = 0; fr < 2; fr++)
            #pragma unroll
            for (int fc = 0; fc < 8; fc++)
                acc[fr][fc] = __builtin_amdgcn_mfma_f32_16x16x32_bf16(
                    a[fr], bb[fc], acc[fr][fc], 0, 0, 0);
    }

    __shared__ float lcol[128];
    if (tid < 128) lcol[tid] = 0.f;
    __syncthreads();

    #pragma unroll
    for (int fc = 0; fc < 8; fc++) {
        float s = 0.f;
        #pragma unroll
        for (int fr = 0; fr < 2; fr++) {
            #pragma unroll
            for (int r = 0; r < 4; r++)
                s += __expf(acc[fr][fc][r] * INV_T);
        }
        s += __shfl_xor(s, 16);
        s += __shfl_xor(s, 32);
        if (quad == 0) atomicAdd(&lcol[fc*16 + n16], s);
    }
    __syncthreads();
    if (tid < 128) atomicAdd(&colsum[b*MM + tj*128 + tid], lcol[tid]);
}

// K3: loss = -mean(diag - log(colsum)) over 8192 entries. 1024 threads,
// 8 elements/thread, float4 loads.
__global__ __launch_bounds__(1024) void finalize(
    const float* __restrict__ colsum, const float* __restrict__ diag,
    float* __restrict__ out)
{
    int tid = threadIdx.x;
    int k0  = tid * 8;
    const float4* cp = (const float4*)(colsum + k0);
    const float4* dp = (const float4*)(diag + k0);
    float4 c0 = cp[0], c1 = cp[1];
    float4 d0 = dp[0], d1 = dp[1];
    float acc = (d0.x - __logf(c0.x)) + (d0.y - __logf(c0.y))
              + (d0.z - __logf(c0.z)) + (d0.w - __logf(c0.w))
              + (d1.x - __logf(c1.x)) + (d1.y - __logf(c1.y))
              + (d1.z - __logf(c1.z)) + (d1.w - __logf(c1.w));
    #pragma unroll
    for (int off = 32; off >= 1; off >>= 1) acc += __shfl_xor(acc, off);
    __shared__ float wsum[16];
    if ((tid & 63) == 0) wsum[tid >> 6] = acc;
    __syncthreads();
    if (tid == 0) {
        float t = 0.f;
        #pragma unroll
        for (int i = 0; i < 16; i++) t += wsum[i];
        out[0] = -t * (1.0f / (NB*MM));
    }
}

extern "C" void kernel_launch(void* const* d_in, const int* in_sizes, int n_in,
                              void* d_out, int out_size, void* d_ws, size_t ws_size,
                              hipStream_t stream)
{
    const float* feats0 = (const float*)d_in[0];
    const float* feats1 = (const float*)d_in[1];
    const int*   corrs  = (const int*)d_in[2];

    char* ws = (char*)d_ws;
    __hip_bfloat16* f0s = (__hip_bfloat16*)ws;                              // 2 MB
    __hip_bfloat16* f1s = (__hip_bfloat16*)(ws + (size_t)NB*MM*DD*2);       // 2 MB
    float* colsum = (float*)(ws + 2*(size_t)NB*MM*DD*2);                    // 32 KB
    float* diag   = colsum + NB*MM;                                         // 32 KB

    gather_pairs<<<(NB*MM)/4, 256, 0, stream>>>(feats0, feats1, corrs,
                                                f0s, f1s, colsum, diag);
    logits_lse<<<dim3(8, 8, NB), 256, 0, stream>>>((const short*)f1s,
                                                   (const short*)f0s, colsum);
    finalize<<<1, 1024, 0, stream>>>(colsum, diag, (float*)d_out);
}